// Round 11
// baseline (70.881 us; speedup 1.0000x reference)
//
#include <hip/hip_runtime.h>
#include <hip/hip_bf16.h>
#include <cstddef>
#include <cstdint>

// ---------------- constants ----------------
#define BATCH 4096
#define TT 26          // sparse tables
#define LL 4           // lookups per table
#define NROWS 100000
#define MM 64          // embedding dim
#define RSTR 512       // padded R row stride (64 + 351 real + 97 pad)

typedef __attribute__((ext_vector_type(8))) short bf16x8;
typedef __attribute__((ext_vector_type(4))) float f32x4;
typedef __attribute__((ext_vector_type(16))) float f32x16;

#define AS1 __attribute__((address_space(1)))
#define AS3 __attribute__((address_space(3)))

__device__ __forceinline__ void gload_lds16(const void* g, void* l) {
    __builtin_amdgcn_global_load_lds((const AS1 unsigned int*)g,
                                     (AS3 unsigned int*)l, 16, 0, 0);
}

__device__ __forceinline__ float bu2f(unsigned short u) {
    unsigned int x = (unsigned int)u << 16;
    float f; __builtin_memcpy(&f, &x, 4); return f;
}

// ---------------- prep: weight conversion (blocks 0..2111) + bot layer 0 ----------------
#define CONV_BLOCKS 2112
__global__ __launch_bounds__(256) void prep_kernel(
    const float* __restrict__ dense, const float* __restrict__ bw0,
    const float* __restrict__ bb0,
    const float* __restrict__ bw1, const float* __restrict__ bw2,
    const float* __restrict__ tw0, const float* __restrict__ tw1,
    __hip_bfloat16* __restrict__ x1,
    __hip_bfloat16* __restrict__ bw1b, __hip_bfloat16* __restrict__ bw2b,
    __hip_bfloat16* __restrict__ tw0b, __hip_bfloat16* __restrict__ tw1b)
{
    __shared__ float xr[13];
    if (blockIdx.x < CONV_BLOCKS) {
        int i = blockIdx.x * 256 + threadIdx.x;
        if (i < 131072) {
            bw1b[i] = __float2bfloat16(bw1[i]);
        } else if (i < 147456) {
            int j = i - 131072; bw2b[j] = __float2bfloat16(bw2[j]);
        } else if (i < 409600) {
            int j = i - 147456; int n = j >> 9, k = j & 511;
            tw0b[j] = __float2bfloat16(k < 415 ? tw0[n * 415 + k] : 0.f);
        } else {
            int j = i - 409600; tw1b[j] = __float2bfloat16(tw1[j]);
        }
        return;
    }
    int b = blockIdx.x - CONV_BLOCKS;
    if (threadIdx.x < 13) xr[threadIdx.x] = dense[b * 13 + threadIdx.x];
    __syncthreads();
    for (int j = threadIdx.x; j < 512; j += 256) {
        const float* w = bw0 + j * 13;
        float s = bb0[j];
#pragma unroll
        for (int k = 0; k < 13; k++) s = fmaf(xr[k], w[k], s);
        x1[(size_t)b * 512 + j] = __float2bfloat16(fmaxf(s, 0.f));
    }
}

// ---------------- full-K bf16 MFMA GEMM: C = relu(A @ W^T + bias) (verified R3/R5) ----------------
template<int KK, int ACT>
__global__ __launch_bounds__(256) void gemm_fullk(
    const __hip_bfloat16* __restrict__ A,
    const __hip_bfloat16* __restrict__ W,
    const float* __restrict__ bias,
    __hip_bfloat16* __restrict__ C, int ldc)
{
    constexpr int HS   = KK / 2;
    constexpr int CPRH = KK / 16;
    constexpr int NI   = (64 * CPRH) / 256;
    __shared__ __align__(16) short As0[64 * HS];
    __shared__ __align__(16) short As1[64 * HS];
    __shared__ __align__(16) short Bs0[64 * HS];
    __shared__ __align__(16) short Bs1[64 * HS];

    const int tid  = threadIdx.x;
    const int lane = tid & 63;
    const int wid  = tid >> 6;
    const int wr   = wid >> 1, wc = wid & 1;

    const char* Ab = (const char*)A + (size_t)blockIdx.x * (64 * KK * 2);
    const char* Wb = (const char*)W + (size_t)blockIdx.y * (64 * KK * 2);

    auto stage = [&](const char* Gb, short* Ls, int h) {
#pragma unroll
        for (int j = 0; j < NI; j++) {
            int ci  = j * 256 + tid;
            int row = ci / CPRH;
            int cb  = (ci & (CPRH - 1)) * 16;
            int src = row * (2 * KK) + h * KK + (cb ^ ((row & 7) << 4));
            gload_lds16(Gb + src, (char*)Ls + row * KK + cb);
        }
    };
    stage(Ab, As0, 0); stage(Wb, Bs0, 0);
    stage(Ab, As1, 1); stage(Wb, Bs1, 1);

    const int frow = lane & 15;
    const int fkb  = (lane >> 4) * 16;
    const int xr   = (frow & 7) << 4;
    const int oA0  = (wr * 32 + frow) * KK;
    const int oA1  = oA0 + 16 * KK;
    const int oB0  = (wc * 32 + frow) * KK;
    const int oB1  = oB0 + 16 * KK;

    f32x4 acc[2][2] = {};

    auto compute = [&](const short* Ah, const short* Bh) {
#pragma unroll
        for (int ks = 0; ks < KK / 64; ks++) {
            int pc = (ks * 64 + fkb) ^ xr;
            bf16x8 a0 = *(const bf16x8*)((const char*)Ah + oA0 + pc);
            bf16x8 a1 = *(const bf16x8*)((const char*)Ah + oA1 + pc);
            bf16x8 b0 = *(const bf16x8*)((const char*)Bh + oB0 + pc);
            bf16x8 b1 = *(const bf16x8*)((const char*)Bh + oB1 + pc);
            acc[0][0] = __builtin_amdgcn_mfma_f32_16x16x32_bf16(a0, b0, acc[0][0], 0, 0, 0);
            acc[0][1] = __builtin_amdgcn_mfma_f32_16x16x32_bf16(a0, b1, acc[0][1], 0, 0, 0);
            acc[1][0] = __builtin_amdgcn_mfma_f32_16x16x32_bf16(a1, b0, acc[1][0], 0, 0, 0);
            acc[1][1] = __builtin_amdgcn_mfma_f32_16x16x32_bf16(a1, b1, acc[1][1], 0, 0, 0);
        }
    };

    asm volatile("s_waitcnt vmcnt(%0)" :: "i"(2 * NI) : "memory");
    __builtin_amdgcn_sched_barrier(0);
    __builtin_amdgcn_s_barrier();
    __builtin_amdgcn_sched_barrier(0);
    compute(As0, Bs0);
    asm volatile("s_waitcnt vmcnt(0)" ::: "memory");
    __builtin_amdgcn_sched_barrier(0);
    __builtin_amdgcn_s_barrier();
    __builtin_amdgcn_sched_barrier(0);
    compute(As1, Bs1);

    const int col0 = blockIdx.y * 64 + wc * 32 + (lane & 15);
    const int row0 = blockIdx.x * 64 + wr * 32 + (lane >> 4) * 4;
    float bias_n0 = bias[col0];
    float bias_n1 = bias[col0 + 16];
#pragma unroll
    for (int mi = 0; mi < 2; mi++) {
#pragma unroll
        for (int j = 0; j < 4; j++) {
            int row = row0 + mi * 16 + j;
            float v0 = acc[mi][0][j] + bias_n0;
            float v1 = acc[mi][1][j] + bias_n1;
            if (ACT == 1) { v0 = fmaxf(v0, 0.f); v1 = fmaxf(v1, 0.f); }
            C[(size_t)row * ldc + col0]      = __float2bfloat16(v0);
            C[(size_t)row * ldc + col0 + 16] = __float2bfloat16(v1);
        }
    }
}

// ---------------- double-buffered GEMM (BK=128, 2 blocks/CU) — top0 only (verified R7/R9/R10) ----------------
template<int KK, int ACT>
__global__ __launch_bounds__(256, 2) void gemm_db(
    const __hip_bfloat16* __restrict__ A,
    const __hip_bfloat16* __restrict__ W,
    const float* __restrict__ bias,
    __hip_bfloat16* __restrict__ C, int ldc)
{
    constexpr int KSTEPS = KK / 128;
    __shared__ __align__(16) short As[2][64 * 128];
    __shared__ __align__(16) short Bs[2][64 * 128];

    const int tid  = threadIdx.x;
    const int lane = tid & 63;
    const int wid  = tid >> 6;
    const int wr   = wid >> 1, wc = wid & 1;

    const char* Ab = (const char*)A + (size_t)blockIdx.x * (64 * KK * 2);
    const char* Wb = (const char*)W + (size_t)blockIdx.y * (64 * KK * 2);

    auto stage = [&](const char* Gb, char* Ls, int ks) {
#pragma unroll
        for (int j = 0; j < 4; j++) {
            int ci  = j * 256 + tid;
            int row = ci >> 4;
            int cb  = (ci & 15) * 16;
            int src = row * (2 * KK) + ks * 256 + (cb ^ ((row & 7) << 4));
            gload_lds16(Gb + src, Ls + row * 256 + cb);
        }
    };

    const int fr  = lane & 15;
    const int fkb = (lane >> 4) * 16;
    const int xrr = (fr & 7) << 4;
    const int oA0 = (wr * 32 + fr) * 256;
    const int oA1 = oA0 + 16 * 256;
    const int oB0 = (wc * 32 + fr) * 256;
    const int oB1 = oB0 + 16 * 256;

    f32x4 acc[2][2] = {};

    auto compute = [&](const char* Ah, const char* Bh) {
#pragma unroll
        for (int kf = 0; kf < 4; kf++) {
            int pc = (kf * 64 + fkb) ^ xrr;
            bf16x8 a0 = *(const bf16x8*)(Ah + oA0 + pc);
            bf16x8 a1 = *(const bf16x8*)(Ah + oA1 + pc);
            bf16x8 b0 = *(const bf16x8*)(Bh + oB0 + pc);
            bf16x8 b1 = *(const bf16x8*)(Bh + oB1 + pc);
            acc[0][0] = __builtin_amdgcn_mfma_f32_16x16x32_bf16(a0, b0, acc[0][0], 0, 0, 0);
            acc[0][1] = __builtin_amdgcn_mfma_f32_16x16x32_bf16(a0, b1, acc[0][1], 0, 0, 0);
            acc[1][0] = __builtin_amdgcn_mfma_f32_16x16x32_bf16(a1, b0, acc[1][0], 0, 0, 0);
            acc[1][1] = __builtin_amdgcn_mfma_f32_16x16x32_bf16(a1, b1, acc[1][1], 0, 0, 0);
        }
    };

    stage(Ab, (char*)As[0], 0); stage(Wb, (char*)Bs[0], 0);
    stage(Ab, (char*)As[1], 1); stage(Wb, (char*)Bs[1], 1);

#pragma unroll
    for (int ks = 0; ks < KSTEPS; ks++) {
        if (ks < KSTEPS - 1) { asm volatile("s_waitcnt vmcnt(8)" ::: "memory"); }
        else                 { asm volatile("s_waitcnt vmcnt(0)" ::: "memory"); }
        __builtin_amdgcn_sched_barrier(0);
        __builtin_amdgcn_s_barrier();
        __builtin_amdgcn_sched_barrier(0);
        compute((const char*)As[ks & 1], (const char*)Bs[ks & 1]);
        __builtin_amdgcn_sched_barrier(0);
        if (ks + 2 < KSTEPS) {
            __builtin_amdgcn_s_barrier();
            stage(Ab, (char*)As[ks & 1], ks + 2);
            stage(Wb, (char*)Bs[ks & 1], ks + 2);
        }
    }

    const int col0 = blockIdx.y * 64 + wc * 32 + (lane & 15);
    const int row0 = blockIdx.x * 64 + wr * 32 + (lane >> 4) * 4;
    float bias_n0 = bias[col0];
    float bias_n1 = bias[col0 + 16];
#pragma unroll
    for (int mi = 0; mi < 2; mi++) {
#pragma unroll
        for (int j = 0; j < 4; j++) {
            int row = row0 + mi * 16 + j;
            float v0 = acc[mi][0][j] + bias_n0;
            float v1 = acc[mi][1][j] + bias_n1;
            if (ACT == 1) { v0 = fmaxf(v0, 0.f); v1 = fmaxf(v1, 0.f); }
            C[(size_t)row * ldc + col0]      = __float2bfloat16(v0);
            C[(size_t)row * ldc + col0 + 16] = __float2bfloat16(v1);
        }
    }
}

// ---------------- fused bot2 + embedding gather + MFMA-Gram interaction ----------------
// 1 batch per block, 4 waves. Gather loads (rows 1..26) issued first (HBM, in
// flight); x3 = relu(x2@W2^T+b2) computed by VALU under that latency (wave w
// owns K-quarter [w*64,w*64+64), LDS partial reduce). Gram = T·T^T via 4x
// mfma_32x32x16 (wave 0), lower-tri -> R[:,64:415]; wave 1 zeroes pad.
__global__ __launch_bounds__(256) void embed_interact_kernel(
    const int* __restrict__ idx, const float* __restrict__ emb,
    const __hip_bfloat16* __restrict__ x2, const __hip_bfloat16* __restrict__ w2b,
    const float* __restrict__ bb2, __hip_bfloat16* __restrict__ R)
{
    __shared__ __align__(16) short T[32 * 64];
    __shared__ int sidx[TT * LL];
    __shared__ float x3p[4][64];
    const int b = blockIdx.x;
    const int tid = threadIdx.x;
    const int lane = tid & 63;
    const int w = tid >> 6;

    if (tid < TT * LL) sidx[tid] = idx[(size_t)b * (TT * LL) + tid];
    // zero pad rows 27..31
    for (int i = tid; i < 5 * 64; i += 256) {
        int r = 27 + (i >> 6), l = i & 63;
        *(short*)((char*)T + r * 128 + ((l * 2) ^ ((r & 7) << 4))) = 0;
    }
    __syncthreads();

    // phase 1: issue all embedding row loads (rows 1..26; up to 28 outstanding/lane)
    float v[7][4];
#pragma unroll
    for (int rr = 0; rr < 7; rr++) {
        const int r = rr * 4 + w;
        if (r >= 1 && r < 27) {
            const int t = r - 1;
            const float* tab = emb + (size_t)t * NROWS * MM + lane;
#pragma unroll
            for (int l = 0; l < LL; l++)
                v[rr][l] = tab[(size_t)sidx[t * LL + l] * MM];
        }
    }

    // phase 2 (hidden under gather latency): x3 partials, wave w = K-quarter w
    {
        const unsigned short* x2q = (const unsigned short*)x2 + (size_t)b * 256 + w * 64;
        const unsigned short* w2q = (const unsigned short*)w2b + (size_t)lane * 256 + w * 64;
        float s = 0.f;
#pragma unroll
        for (int k = 0; k < 64; k += 4) {
            ushort4 xa = *(const ushort4*)&x2q[k];
            ushort4 wa = *(const ushort4*)&w2q[k];
            s += bu2f(xa.x) * bu2f(wa.x) + bu2f(xa.y) * bu2f(wa.y)
               + bu2f(xa.z) * bu2f(wa.z) + bu2f(xa.w) * bu2f(wa.w);
        }
        x3p[w][lane] = s;
    }
    __syncthreads();

    // x3 reduce -> T row 0 (swizzle XOR = 0 for row 0) + R[:,0:64]
    if (tid < 64) {
        float xv = x3p[0][tid] + x3p[1][tid] + x3p[2][tid] + x3p[3][tid] + bb2[tid];
        __hip_bfloat16 hv = __float2bfloat16(fmaxf(xv, 0.f));
        *(short*)((char*)T + tid * 2) = *(short*)&hv;
        R[(size_t)b * RSTR + tid] = hv;
    }

    // phase 3: consume gather loads -> T rows 1..26
#pragma unroll
    for (int rr = 0; rr < 7; rr++) {
        const int r = rr * 4 + w;
        if (r >= 1 && r < 27) {
            float s = v[rr][0] + v[rr][1] + v[rr][2] + v[rr][3];
            __hip_bfloat16 hv = __float2bfloat16(s);
            *(short*)((char*)T + r * 128 + ((lane * 2) ^ ((r & 7) << 4))) = *(short*)&hv;
        }
    }
    __syncthreads();

    __hip_bfloat16* Rb = R + (size_t)b * RSTR;
    if (w == 1) {
        Rb[415 + lane] = __float2bfloat16(0.f);
        if (lane < 33) Rb[479 + lane] = __float2bfloat16(0.f);
    }
    if (w == 0) {
        f32x16 acc = {};
#pragma unroll
        for (int m = 0; m < 4; m++) {
            int byteoff = (lane & 31) * 128 +
                          ((m * 32 + (lane >> 5) * 16) ^ ((lane & 7) << 4));
            bf16x8 f = *(const bf16x8*)((const char*)T + byteoff);
            acc = __builtin_amdgcn_mfma_f32_32x32x16_bf16(f, f, acc, 0, 0, 0);
        }
        const int col = lane & 31;
#pragma unroll
        for (int q = 0; q < 4; q++) {
#pragma unroll
            for (int j = 0; j < 4; j++) {
                int row = j + 8 * q + 4 * (lane >> 5);
                if (row < 27 && col < row)
                    Rb[64 + row * (row - 1) / 2 + col] = __float2bfloat16(acc[q * 4 + j]);
            }
        }
    }
}

// ---------------- top layer 2: (4096,256) bf16 -> (4096,1), sigmoid ----------------
__global__ __launch_bounds__(256) void top2_kernel(
    const __hip_bfloat16* __restrict__ h, const float* __restrict__ W,
    const float* __restrict__ bias, float* __restrict__ out)
{
    __shared__ float ws[256];
    int tid = threadIdx.x;
    ws[tid] = W[tid];
    __syncthreads();
    int b = blockIdx.x * 4 + (tid >> 6);
    int lane = tid & 63;
    const unsigned short* hb = (const unsigned short*)(h + (size_t)b * 256);
    ushort4 hv = *(const ushort4*)&hb[lane * 4];
    float4 wv = *(const float4*)&ws[lane * 4];
    float s = bu2f(hv.x) * wv.x + bu2f(hv.y) * wv.y + bu2f(hv.z) * wv.z + bu2f(hv.w) * wv.w;
#pragma unroll
    for (int off = 32; off >= 1; off >>= 1)
        s += __shfl_xor(s, off, 64);
    if (lane == 0) {
        float v = s + bias[0];
        out[b] = 1.0f / (1.0f + expf(-v));
    }
}

// ---------------- launch ----------------
extern "C" void kernel_launch(void* const* d_in, const int* in_sizes, int n_in,
                              void* d_out, int out_size, void* d_ws, size_t ws_size,
                              hipStream_t stream) {
    const float* dense = (const float*)d_in[0];
    const int*   sidx  = (const int*)d_in[1];
    const float* emb   = (const float*)d_in[2];
    const float* bw0   = (const float*)d_in[3];
    const float* bb0   = (const float*)d_in[4];
    const float* bw1   = (const float*)d_in[5];
    const float* bb1   = (const float*)d_in[6];
    const float* bw2   = (const float*)d_in[7];
    const float* bb2   = (const float*)d_in[8];
    const float* tw0   = (const float*)d_in[9];
    const float* tb0   = (const float*)d_in[10];
    const float* tw1   = (const float*)d_in[11];
    const float* tb1   = (const float*)d_in[12];
    const float* tw2   = (const float*)d_in[13];
    const float* tb2   = (const float*)d_in[14];
    float* out = (float*)d_out;

    char* wsb = (char*)d_ws;
    __hip_bfloat16* x1   = (__hip_bfloat16*)(wsb);                 // 4096x512
    __hip_bfloat16* x2   = (__hip_bfloat16*)(wsb + (4u << 20));    // 4096x256
    __hip_bfloat16* R    = (__hip_bfloat16*)(wsb + (8u << 20));    // 4096x512
    __hip_bfloat16* h1   = (__hip_bfloat16*)(wsb + (12u << 20));   // 4096x512
    __hip_bfloat16* h2   = (__hip_bfloat16*)(wsb + (16u << 20));   // 4096x256
    __hip_bfloat16* bw1b = (__hip_bfloat16*)(wsb + (18u << 20));   // 256x512
    __hip_bfloat16* bw2b = bw1b + 131072;                          // 64x256
    __hip_bfloat16* tw0b = bw2b + 16384;                           // 512x512
    __hip_bfloat16* tw1b = tw0b + 262144;                          // 256x512

    // 1. weight conversion + bottom layer 0
    prep_kernel<<<CONV_BLOCKS + BATCH, 256, 0, stream>>>(
        dense, bw0, bb0, bw1, bw2, tw0, tw1, x1, bw1b, bw2b, tw0b, tw1b);

    // 2. bottom layer 1: x1 (4096,512) -> x2 (4096,256)   [256 blocks -> fullk]
    gemm_fullk<512, 1><<<dim3(64, 4), 256, 0, stream>>>(x1, bw1b, bb1, x2, 256);

    // 3. fused bot2 + embedding + Gram interaction -> R (4096,512)
    embed_interact_kernel<<<BATCH, 256, 0, stream>>>(sidx, emb, x2, bw2b, bb2, R);

    // 4. top layer 0: R (4096,512) -> h1 (4096,512)       [512 blocks -> db, 2/CU]
    gemm_db<512, 1><<<dim3(64, 8), 256, 0, stream>>>(R, tw0b, tb0, h1, 512);

    // 5. top layer 1: h1 (4096,512) -> h2 (4096,256)      [256 blocks -> fullk]
    gemm_fullk<512, 1><<<dim3(64, 4), 256, 0, stream>>>(h1, tw1b, tb1, h2, 256);

    // 6. top layer 2: h2 -> out, sigmoid
    top2_kernel<<<BATCH / 4, 256, 0, stream>>>(h2, tw2, tb2, out);
}

// Round 12
// 53.134 us; speedup vs baseline: 1.3340x; 1.3340x over previous
//
#include <hip/hip_runtime.h>
#include <hip/hip_bf16.h>
#include <cstddef>
#include <cstdint>

// ---------------- constants ----------------
#define BATCH 4096
#define TT 26          // sparse tables
#define LL 4           // lookups per table
#define NROWS 100000
#define MM 64          // embedding dim
#define RSTR 512       // padded R row stride (64 + 351 real + 97 pad)

typedef __attribute__((ext_vector_type(8))) short bf16x8;
typedef __attribute__((ext_vector_type(4))) float f32x4;
typedef __attribute__((ext_vector_type(16))) float f32x16;

#define AS1 __attribute__((address_space(1)))
#define AS3 __attribute__((address_space(3)))

__device__ __forceinline__ void gload_lds16(const void* g, void* l) {
    __builtin_amdgcn_global_load_lds((const AS1 unsigned int*)g,
                                     (AS3 unsigned int*)l, 16, 0, 0);
}

__device__ __forceinline__ float bu2f(unsigned short u) {
    unsigned int x = (unsigned int)u << 16;
    float f; __builtin_memcpy(&f, &x, 4); return f;
}

// ---------------- prep: weight conversion (blocks 0..2111) + bot layer 0 ----------------
#define CONV_BLOCKS 2112
__global__ __launch_bounds__(256) void prep_kernel(
    const float* __restrict__ dense, const float* __restrict__ bw0,
    const float* __restrict__ bb0,
    const float* __restrict__ bw1, const float* __restrict__ bw2,
    const float* __restrict__ tw0, const float* __restrict__ tw1,
    __hip_bfloat16* __restrict__ x1,
    __hip_bfloat16* __restrict__ bw1b, __hip_bfloat16* __restrict__ bw2b,
    __hip_bfloat16* __restrict__ tw0b, __hip_bfloat16* __restrict__ tw1b)
{
    __shared__ float xr[13];
    if (blockIdx.x < CONV_BLOCKS) {
        int i = blockIdx.x * 256 + threadIdx.x;
        if (i < 131072) {
            bw1b[i] = __float2bfloat16(bw1[i]);
        } else if (i < 147456) {
            int j = i - 131072; bw2b[j] = __float2bfloat16(bw2[j]);
        } else if (i < 409600) {
            int j = i - 147456; int n = j >> 9, k = j & 511;
            tw0b[j] = __float2bfloat16(k < 415 ? tw0[n * 415 + k] : 0.f);
        } else {
            int j = i - 409600; tw1b[j] = __float2bfloat16(tw1[j]);
        }
        return;
    }
    int b = blockIdx.x - CONV_BLOCKS;
    if (threadIdx.x < 13) xr[threadIdx.x] = dense[b * 13 + threadIdx.x];
    __syncthreads();
    for (int j = threadIdx.x; j < 512; j += 256) {
        const float* w = bw0 + j * 13;
        float s = bb0[j];
#pragma unroll
        for (int k = 0; k < 13; k++) s = fmaf(xr[k], w[k], s);
        x1[(size_t)b * 512 + j] = __float2bfloat16(fmaxf(s, 0.f));
    }
}

// ---------------- full-K bf16 MFMA GEMM: C = relu(A @ W^T + bias) (verified R3/R5) ----------------
// Deep prefetch (whole K panel, 32 loads in flight); best for grids <= 256 blocks.
template<int KK, int ACT>
__global__ __launch_bounds__(256) void gemm_fullk(
    const __hip_bfloat16* __restrict__ A,
    const __hip_bfloat16* __restrict__ W,
    const float* __restrict__ bias,
    __hip_bfloat16* __restrict__ C, int ldc)
{
    constexpr int HS   = KK / 2;
    constexpr int CPRH = KK / 16;
    constexpr int NI   = (64 * CPRH) / 256;
    __shared__ __align__(16) short As0[64 * HS];
    __shared__ __align__(16) short As1[64 * HS];
    __shared__ __align__(16) short Bs0[64 * HS];
    __shared__ __align__(16) short Bs1[64 * HS];

    const int tid  = threadIdx.x;
    const int lane = tid & 63;
    const int wid  = tid >> 6;
    const int wr   = wid >> 1, wc = wid & 1;

    const char* Ab = (const char*)A + (size_t)blockIdx.x * (64 * KK * 2);
    const char* Wb = (const char*)W + (size_t)blockIdx.y * (64 * KK * 2);

    auto stage = [&](const char* Gb, short* Ls, int h) {
#pragma unroll
        for (int j = 0; j < NI; j++) {
            int ci  = j * 256 + tid;
            int row = ci / CPRH;
            int cb  = (ci & (CPRH - 1)) * 16;
            int src = row * (2 * KK) + h * KK + (cb ^ ((row & 7) << 4));
            gload_lds16(Gb + src, (char*)Ls + row * KK + cb);
        }
    };
    stage(Ab, As0, 0); stage(Wb, Bs0, 0);
    stage(Ab, As1, 1); stage(Wb, Bs1, 1);

    const int frow = lane & 15;
    const int fkb  = (lane >> 4) * 16;
    const int xr   = (frow & 7) << 4;
    const int oA0  = (wr * 32 + frow) * KK;
    const int oA1  = oA0 + 16 * KK;
    const int oB0  = (wc * 32 + frow) * KK;
    const int oB1  = oB0 + 16 * KK;

    f32x4 acc[2][2] = {};

    auto compute = [&](const short* Ah, const short* Bh) {
#pragma unroll
        for (int ks = 0; ks < KK / 64; ks++) {
            int pc = (ks * 64 + fkb) ^ xr;
            bf16x8 a0 = *(const bf16x8*)((const char*)Ah + oA0 + pc);
            bf16x8 a1 = *(const bf16x8*)((const char*)Ah + oA1 + pc);
            bf16x8 b0 = *(const bf16x8*)((const char*)Bh + oB0 + pc);
            bf16x8 b1 = *(const bf16x8*)((const char*)Bh + oB1 + pc);
            acc[0][0] = __builtin_amdgcn_mfma_f32_16x16x32_bf16(a0, b0, acc[0][0], 0, 0, 0);
            acc[0][1] = __builtin_amdgcn_mfma_f32_16x16x32_bf16(a0, b1, acc[0][1], 0, 0, 0);
            acc[1][0] = __builtin_amdgcn_mfma_f32_16x16x32_bf16(a1, b0, acc[1][0], 0, 0, 0);
            acc[1][1] = __builtin_amdgcn_mfma_f32_16x16x32_bf16(a1, b1, acc[1][1], 0, 0, 0);
        }
    };

    asm volatile("s_waitcnt vmcnt(%0)" :: "i"(2 * NI) : "memory");
    __builtin_amdgcn_sched_barrier(0);
    __builtin_amdgcn_s_barrier();
    __builtin_amdgcn_sched_barrier(0);
    compute(As0, Bs0);
    asm volatile("s_waitcnt vmcnt(0)" ::: "memory");
    __builtin_amdgcn_sched_barrier(0);
    __builtin_amdgcn_s_barrier();
    __builtin_amdgcn_sched_barrier(0);
    compute(As1, Bs1);

    const int col0 = blockIdx.y * 64 + wc * 32 + (lane & 15);
    const int row0 = blockIdx.x * 64 + wr * 32 + (lane >> 4) * 4;
    float bias_n0 = bias[col0];
    float bias_n1 = bias[col0 + 16];
#pragma unroll
    for (int mi = 0; mi < 2; mi++) {
#pragma unroll
        for (int j = 0; j < 4; j++) {
            int row = row0 + mi * 16 + j;
            float v0 = acc[mi][0][j] + bias_n0;
            float v1 = acc[mi][1][j] + bias_n1;
            if (ACT == 1) { v0 = fmaxf(v0, 0.f); v1 = fmaxf(v1, 0.f); }
            C[(size_t)row * ldc + col0]      = __float2bfloat16(v0);
            C[(size_t)row * ldc + col0 + 16] = __float2bfloat16(v1);
        }
    }
}

// ---------------- double-buffered GEMM (BK=128, 2 blocks/CU) — top0 only (verified R7/R9/R10) ----------------
template<int KK, int ACT>
__global__ __launch_bounds__(256, 2) void gemm_db(
    const __hip_bfloat16* __restrict__ A,
    const __hip_bfloat16* __restrict__ W,
    const float* __restrict__ bias,
    __hip_bfloat16* __restrict__ C, int ldc)
{
    constexpr int KSTEPS = KK / 128;
    __shared__ __align__(16) short As[2][64 * 128];
    __shared__ __align__(16) short Bs[2][64 * 128];

    const int tid  = threadIdx.x;
    const int lane = tid & 63;
    const int wid  = tid >> 6;
    const int wr   = wid >> 1, wc = wid & 1;

    const char* Ab = (const char*)A + (size_t)blockIdx.x * (64 * KK * 2);
    const char* Wb = (const char*)W + (size_t)blockIdx.y * (64 * KK * 2);

    auto stage = [&](const char* Gb, char* Ls, int ks) {
#pragma unroll
        for (int j = 0; j < 4; j++) {
            int ci  = j * 256 + tid;
            int row = ci >> 4;
            int cb  = (ci & 15) * 16;
            int src = row * (2 * KK) + ks * 256 + (cb ^ ((row & 7) << 4));
            gload_lds16(Gb + src, Ls + row * 256 + cb);
        }
    };

    const int fr  = lane & 15;
    const int fkb = (lane >> 4) * 16;
    const int xrr = (fr & 7) << 4;
    const int oA0 = (wr * 32 + fr) * 256;
    const int oA1 = oA0 + 16 * 256;
    const int oB0 = (wc * 32 + fr) * 256;
    const int oB1 = oB0 + 16 * 256;

    f32x4 acc[2][2] = {};

    auto compute = [&](const char* Ah, const char* Bh) {
#pragma unroll
        for (int kf = 0; kf < 4; kf++) {
            int pc = (kf * 64 + fkb) ^ xrr;
            bf16x8 a0 = *(const bf16x8*)(Ah + oA0 + pc);
            bf16x8 a1 = *(const bf16x8*)(Ah + oA1 + pc);
            bf16x8 b0 = *(const bf16x8*)(Bh + oB0 + pc);
            bf16x8 b1 = *(const bf16x8*)(Bh + oB1 + pc);
            acc[0][0] = __builtin_amdgcn_mfma_f32_16x16x32_bf16(a0, b0, acc[0][0], 0, 0, 0);
            acc[0][1] = __builtin_amdgcn_mfma_f32_16x16x32_bf16(a0, b1, acc[0][1], 0, 0, 0);
            acc[1][0] = __builtin_amdgcn_mfma_f32_16x16x32_bf16(a1, b0, acc[1][0], 0, 0, 0);
            acc[1][1] = __builtin_amdgcn_mfma_f32_16x16x32_bf16(a1, b1, acc[1][1], 0, 0, 0);
        }
    };

    stage(Ab, (char*)As[0], 0); stage(Wb, (char*)Bs[0], 0);
    stage(Ab, (char*)As[1], 1); stage(Wb, (char*)Bs[1], 1);

#pragma unroll
    for (int ks = 0; ks < KSTEPS; ks++) {
        if (ks < KSTEPS - 1) { asm volatile("s_waitcnt vmcnt(8)" ::: "memory"); }
        else                 { asm volatile("s_waitcnt vmcnt(0)" ::: "memory"); }
        __builtin_amdgcn_sched_barrier(0);
        __builtin_amdgcn_s_barrier();
        __builtin_amdgcn_sched_barrier(0);
        compute((const char*)As[ks & 1], (const char*)Bs[ks & 1]);
        __builtin_amdgcn_sched_barrier(0);
        if (ks + 2 < KSTEPS) {
            __builtin_amdgcn_s_barrier();
            stage(Ab, (char*)As[ks & 1], ks + 2);
            stage(Wb, (char*)Bs[ks & 1], ks + 2);
        }
    }

    const int col0 = blockIdx.y * 64 + wc * 32 + (lane & 15);
    const int row0 = blockIdx.x * 64 + wr * 32 + (lane >> 4) * 4;
    float bias_n0 = bias[col0];
    float bias_n1 = bias[col0 + 16];
#pragma unroll
    for (int mi = 0; mi < 2; mi++) {
#pragma unroll
        for (int j = 0; j < 4; j++) {
            int row = row0 + mi * 16 + j;
            float v0 = acc[mi][0][j] + bias_n0;
            float v1 = acc[mi][1][j] + bias_n1;
            if (ACT == 1) { v0 = fmaxf(v0, 0.f); v1 = fmaxf(v1, 0.f); }
            C[(size_t)row * ldc + col0]      = __float2bfloat16(v0);
            C[(size_t)row * ldc + col0 + 16] = __float2bfloat16(v1);
        }
    }
}

// ---------------- fused embedding gather + MFMA-Gram interaction (verified R5/R10) ----------------
// 1 batch per block, 4 waves. Gather: wave w loads rows r = rr*4+w (row 0 = x3
// from R, written by bot2). Rows stored bf16 into XOR-swizzled T (32x64).
// Gram: wave 0 computes T·T^T via 4x mfma_32x32x16_bf16 (A-frag == B-frag),
// writes lower-triangle to R[:, 64:415]; wave 1 zeroes R[:, 415:512].
__global__ __launch_bounds__(256) void embed_interact_kernel(
    const int* __restrict__ idx, const float* __restrict__ emb,
    __hip_bfloat16* __restrict__ R)
{
    __shared__ __align__(16) short T[32 * 64];
    __shared__ int sidx[TT * LL];
    const int b = blockIdx.x;
    const int tid = threadIdx.x;
    const int lane = tid & 63;
    const int w = tid >> 6;

    if (tid < TT * LL) sidx[tid] = idx[(size_t)b * (TT * LL) + tid];
    // zero pad rows 27..31
    for (int i = tid; i < 5 * 64; i += 256) {
        int r = 27 + (i >> 6), l = i & 63;
        *(short*)((char*)T + r * 128 + ((l * 2) ^ ((r & 7) << 4))) = 0;
    }
    __syncthreads();

    // phase 1: issue all row loads into registers (28 outstanding/lane), then sum
    float v[7][4];
#pragma unroll
    for (int rr = 0; rr < 7; rr++) {
        const int r = rr * 4 + w;
        if (r == 0) {
            v[rr][0] = __bfloat162float(R[(size_t)b * RSTR + lane]);
            v[rr][1] = 0.f; v[rr][2] = 0.f; v[rr][3] = 0.f;
        } else if (r < 27) {
            const int t = r - 1;
            const float* tab = emb + (size_t)t * NROWS * MM + lane;
#pragma unroll
            for (int l = 0; l < LL; l++)
                v[rr][l] = tab[(size_t)sidx[t * LL + l] * MM];
        }
    }
#pragma unroll
    for (int rr = 0; rr < 7; rr++) {
        const int r = rr * 4 + w;
        if (r < 27) {
            float s = v[rr][0] + v[rr][1] + v[rr][2] + v[rr][3];
            __hip_bfloat16 hv = __float2bfloat16(s);
            *(short*)((char*)T + r * 128 + ((lane * 2) ^ ((r & 7) << 4))) = *(short*)&hv;
        }
    }
    __syncthreads();

    __hip_bfloat16* Rb = R + (size_t)b * RSTR;
    if (w == 1) {
        Rb[415 + lane] = __float2bfloat16(0.f);
        if (lane < 33) Rb[479 + lane] = __float2bfloat16(0.f);
    }
    if (w == 0) {
        f32x16 acc = {};
#pragma unroll
        for (int m = 0; m < 4; m++) {
            int byteoff = (lane & 31) * 128 +
                          ((m * 32 + (lane >> 5) * 16) ^ ((lane & 7) << 4));
            bf16x8 f = *(const bf16x8*)((const char*)T + byteoff);
            acc = __builtin_amdgcn_mfma_f32_32x32x16_bf16(f, f, acc, 0, 0, 0);
        }
        const int col = lane & 31;
#pragma unroll
        for (int q = 0; q < 4; q++) {
#pragma unroll
            for (int j = 0; j < 4; j++) {
                int row = j + 8 * q + 4 * (lane >> 5);
                if (row < 27 && col < row)
                    Rb[64 + row * (row - 1) / 2 + col] = __float2bfloat16(acc[q * 4 + j]);
            }
        }
    }
}

// ---------------- top layer 2: (4096,256) bf16 -> (4096,1), sigmoid ----------------
__global__ __launch_bounds__(256) void top2_kernel(
    const __hip_bfloat16* __restrict__ h, const float* __restrict__ W,
    const float* __restrict__ bias, float* __restrict__ out)
{
    __shared__ float ws[256];
    int tid = threadIdx.x;
    ws[tid] = W[tid];
    __syncthreads();
    int b = blockIdx.x * 4 + (tid >> 6);
    int lane = tid & 63;
    const unsigned short* hb = (const unsigned short*)(h + (size_t)b * 256);
    ushort4 hv = *(const ushort4*)&hb[lane * 4];
    float4 wv = *(const float4*)&ws[lane * 4];
    float s = bu2f(hv.x) * wv.x + bu2f(hv.y) * wv.y + bu2f(hv.z) * wv.z + bu2f(hv.w) * wv.w;
#pragma unroll
    for (int off = 32; off >= 1; off >>= 1)
        s += __shfl_xor(s, off, 64);
    if (lane == 0) {
        float v = s + bias[0];
        out[b] = 1.0f / (1.0f + expf(-v));
    }
}

// ---------------- launch ----------------
extern "C" void kernel_launch(void* const* d_in, const int* in_sizes, int n_in,
                              void* d_out, int out_size, void* d_ws, size_t ws_size,
                              hipStream_t stream) {
    const float* dense = (const float*)d_in[0];
    const int*   sidx  = (const int*)d_in[1];
    const float* emb   = (const float*)d_in[2];
    const float* bw0   = (const float*)d_in[3];
    const float* bb0   = (const float*)d_in[4];
    const float* bw1   = (const float*)d_in[5];
    const float* bb1   = (const float*)d_in[6];
    const float* bw2   = (const float*)d_in[7];
    const float* bb2   = (const float*)d_in[8];
    const float* tw0   = (const float*)d_in[9];
    const float* tb0   = (const float*)d_in[10];
    const float* tw1   = (const float*)d_in[11];
    const float* tb1   = (const float*)d_in[12];
    const float* tw2   = (const float*)d_in[13];
    const float* tb2   = (const float*)d_in[14];
    float* out = (float*)d_out;

    char* wsb = (char*)d_ws;
    __hip_bfloat16* x1   = (__hip_bfloat16*)(wsb);                 // 4096x512
    __hip_bfloat16* x2   = (__hip_bfloat16*)(wsb + (4u << 20));    // 4096x256
    __hip_bfloat16* R    = (__hip_bfloat16*)(wsb + (8u << 20));    // 4096x512
    __hip_bfloat16* h1   = (__hip_bfloat16*)(wsb + (12u << 20));   // 4096x512
    __hip_bfloat16* h2   = (__hip_bfloat16*)(wsb + (16u << 20));   // 4096x256
    __hip_bfloat16* bw1b = (__hip_bfloat16*)(wsb + (18u << 20));   // 256x512
    __hip_bfloat16* bw2b = bw1b + 131072;                          // 64x256
    __hip_bfloat16* tw0b = bw2b + 16384;                           // 512x512
    __hip_bfloat16* tw1b = tw0b + 262144;                          // 256x512

    // 1. weight conversion + bottom layer 0
    prep_kernel<<<CONV_BLOCKS + BATCH, 256, 0, stream>>>(
        dense, bw0, bb0, bw1, bw2, tw0, tw1, x1, bw1b, bw2b, tw0b, tw1b);

    // 2. bottom layer 1: x1 (4096,512) -> x2 (4096,256)   [256 blocks -> fullk]
    gemm_fullk<512, 1><<<dim3(64, 4), 256, 0, stream>>>(x1, bw1b, bb1, x2, 256);

    // 3. bottom layer 2: x2 (4096,256) -> R[:, 0:64]      [64 blocks -> fullk]
    gemm_fullk<256, 1><<<dim3(64, 1), 256, 0, stream>>>(x2, bw2b, bb2, R, RSTR);

    // 4. fused embedding + Gram interaction -> R[:, 64:512]
    embed_interact_kernel<<<BATCH, 256, 0, stream>>>(sidx, emb, R);

    // 5. top layer 0: R (4096,512) -> h1 (4096,512)       [512 blocks -> db, 2/CU]
    gemm_db<512, 1><<<dim3(64, 8), 256, 0, stream>>>(R, tw0b, tb0, h1, 512);

    // 6. top layer 1: h1 (4096,512) -> h2 (4096,256)      [256 blocks -> fullk]
    gemm_fullk<512, 1><<<dim3(64, 4), 256, 0, stream>>>(h1, tw1b, tb1, h2, 256);

    // 7. top layer 2: h2 -> out, sigmoid
    top2_kernel<<<BATCH / 4, 256, 0, stream>>>(h2, tw2, tb2, out);
}